// Round 1
// baseline (139.042 us; speedup 1.0000x reference)
//
#include <hip/hip_runtime.h>
#include <stdint.h>

#define C_CH 192
#define HW   4096
#define NB   16
#define NO   5

typedef __attribute__((ext_vector_type(8)))  short short8;
typedef __attribute__((ext_vector_type(16))) float floatx16;

__device__ __forceinline__ unsigned short f2bf(float f) {
    unsigned int u = __float_as_uint(f);
    unsigned int r = (u + 0x7fffu + ((u >> 16) & 1u)) >> 16;  // RNE to bf16
    return (unsigned short)r;
}

__device__ __forceinline__ uint4 s8u4(short8 f) { return *(uint4*)&f; }

// shift fragment toward lower index: out[j] = {ex, f[0..6]}   (dx = -1)
__device__ __forceinline__ short8 shift_m(short8 f, unsigned short ex) {
    uint4 v = *(uint4*)&f; uint4 w;
    w.x = (unsigned)ex   | (v.x << 16);
    w.y = (v.x >> 16)    | (v.y << 16);
    w.z = (v.y >> 16)    | (v.z << 16);
    w.w = (v.z >> 16)    | (v.w << 16);
    return *(short8*)&w;
}
// shift toward higher index: out[j] = {f[1..7], ex}   (dx = +1)
__device__ __forceinline__ short8 shift_p(short8 f, unsigned short ex) {
    uint4 v = *(uint4*)&f; uint4 w;
    w.x = (v.x >> 16) | (v.y << 16);
    w.y = (v.y >> 16) | (v.z << 16);
    w.z = (v.z >> 16) | (v.w << 16);
    w.w = (v.w >> 16) | ((unsigned)ex << 16);
    return *(short8*)&w;
}

// Build shifted variants of the 16-elem k-step fragment held as Uarr[S] across the
// lo=0/lo=1 half-waves. Edge elements come from the partner lane (lane^32) via shfl,
// with w=0 / w=63 clamps at S==0 (lo=0) and S==3 (lo=1).
#define MAKE_SHIFT(Uarr, S, Um, Up)                                              \
    do {                                                                         \
        uint4 _u0 = s8u4(Uarr[(S) > 0 ? (S) - 1 : 0]);                           \
        uint4 _u1 = s8u4(Uarr[S]);                                               \
        uint4 _u2 = s8u4(Uarr[(S) < 3 ? (S) + 1 : 3]);                           \
        unsigned _sm = lo ? _u0.w : _u1.w;                                       \
        unsigned _sp = lo ? _u1.x : _u2.x;                                       \
        unsigned _rm = (unsigned)__shfl_xor((int)_sm, 32, 64);                   \
        unsigned _rp = (unsigned)__shfl_xor((int)_sp, 32, 64);                   \
        unsigned short _exm = (unsigned short)(_rm >> 16);                       \
        if ((S) == 0) _exm = lo ? _exm : (unsigned short)(_u1.x & 0xffffu);      \
        unsigned short _exp = (unsigned short)(_rp & 0xffffu);                   \
        if ((S) == 3) _exp = lo ? (unsigned short)(_u1.w >> 16) : _exp;          \
        Um = shift_m(Uarr[S], _exm);                                             \
        Up = shift_p(Uarr[S], _exp);                                             \
    } while (0)

// Minus-only variant (pass A needs just Um): 1 shfl instead of 2.
#define MAKE_SHIFT_M(Uarr, S, Um)                                                \
    do {                                                                         \
        uint4 _u0 = s8u4(Uarr[(S) > 0 ? (S) - 1 : 0]);                           \
        uint4 _u1 = s8u4(Uarr[S]);                                               \
        unsigned _sm = lo ? _u0.w : _u1.w;                                       \
        unsigned _rm = (unsigned)__shfl_xor((int)_sm, 32, 64);                   \
        unsigned short _exm = (unsigned short)(_rm >> 16);                       \
        if ((S) == 0) _exm = lo ? _exm : (unsigned short)(_u1.x & 0xffffu);      \
        Um = shift_m(Uarr[S], _exm);                                             \
    } while (0)

// ---------------- Kernel 1: fp32 -> bf16, fragment-tiled layout ----------------
// xb short8 index: grp*16384 + q*32 + c'    (grp = b*6+cb, q = k>>3, c' = ch&31)
// Lane mapping: idx bits [13:8]=qhi [7:3]=c' [2:0]=qlo; q = qhi*8+qlo.
__global__ __launch_bounds__(256) void convert_kernel(const float* __restrict__ x,
                                                      unsigned short* __restrict__ xb,
                                                      float* __restrict__ norms) {
    if (blockIdx.x == 0 && threadIdx.x < NB * NO) norms[threadIdx.x] = 0.0f;
    int t   = blockIdx.x * 256 + threadIdx.x;   // 1,572,864 threads
    int grp = t >> 14;                          // 96 groups of (b, cb)
    int idx = t & 16383;
    int qhi = idx >> 8;
    int cp  = (idx >> 3) & 31;
    int qlo = idx & 7;
    int q   = qhi * 8 + qlo;
    int b   = grp / 6;
    int cb  = grp - b * 6;
    int ch  = cb * 32 + cp;
    const float4* p = (const float4*)(x + (size_t)(b * C_CH + ch) * HW + q * 8);
    float4 v0 = p[0], v1 = p[1];
    ushort4 o0, o1;
    o0.x = f2bf(v0.x); o0.y = f2bf(v0.y); o0.z = f2bf(v0.z); o0.w = f2bf(v0.w);
    o1.x = f2bf(v1.x); o1.y = f2bf(v1.y); o1.z = f2bf(v1.z); o1.w = f2bf(v1.w);
    ushort4* dst = (ushort4*)xb + ((size_t)grp * 16384 + q * 32 + cp) * 2;
    dst[0] = o0; dst[1] = o1;
}

// ---------------- Kernel 2: fused 5-offset Gram, two-pass offset split ----------------
// grid 576 = 16 b x 36 (32x32)-tiles; 512 threads = 8 waves; wave wv covers h-rows
// [8wv, 8wv+8).
//
// R5 change: the old single-pass version held 5x16=80 AGPR of accumulator + ~84 VGPR
// = ~164 unified regs/wave -> 3 waves/SIMD -> only ONE 8-wave block/CU resident
// (12-slot capacity can't fit a second 8-wave block). MfmaUtil was 19.6% with the
// MFMA floor at 9.7us vs 46us measured: latency-bound at 2 waves/SIMD.
// Split offsets into two sequential passes so peak acc = 48 AGPR and total live
// regs <= 128 (__launch_bounds__(512,4) enforces) -> 16 waves/CU = 2 blocks/CU
// = 4 waves/SIMD. Rows are streamed twice (block loads ~1.2MB vs 512KB), still
// L2-resident per XCD (~3MB working set).
//
//   pass A: offsets 3:(0,-1) 4:(0,0)   : acc += A[g] * {Um,U}[g]
//   pass B: offsets 0:(-1,-1) 1:(-1,0) 2:(-1,1) : acc += A[g+1] * {Um,U,Up}[g],
//           g = 0..62, plus h=0 boundary A[0]*{Um,U,Up}[0] (wave 0).
__global__ __launch_bounds__(512, 4) void cofe_gemm(const unsigned short* __restrict__ xb,
                                                    float* __restrict__ out,
                                                    float* __restrict__ norms) {
    int blk  = blockIdx.x;
    int work = (blk & 7) * 72 + (blk >> 3);     // XCD swizzle: 2 batches per XCD
    int b = work / 36;
    int t = work % 36;
    int cbA = t / 6, cbB = t % 6;
    int c0 = cbA * 32, d0 = cbB * 32;

    int wv   = threadIdx.x >> 6;                // 0..7
    int lane = threadIdx.x & 63;
    int lr   = lane & 31;
    int lo   = lane >> 5;
    int laneoff = lo * 32 + lr;                 // short8 units

    const short8* A8 = (const short8*)xb + (size_t)(b * 6 + cbA) * 16384;
    const short8* B8 = (const short8*)xb + (size_t)(b * 6 + cbB) * 16384;

    int h0 = wv * 8;

    __shared__ float red[8192];   // 32 KB
    __shared__ float wsum[4];
    float4* red4 = (float4*)red;
    size_t obase = (size_t)b * NO * (C_CH * C_CH);
    int tt = threadIdx.x;

#define REDUCE_STORE(ACC, O)                                                     \
    do {                                                                         \
        __syncthreads();                                                         \
        _Pragma("unroll")                                                        \
        for (int reg = 0; reg < 16; ++reg) {                                     \
            int row_ = (reg & 3) + 8 * (reg >> 2) + 4 * lo;  /* C/D layout */    \
            red[wv * 1024 + row_ * 32 + lr] = ACC[reg];                          \
        }                                                                        \
        __syncthreads();                                                         \
        if (tt < 256) {                                                          \
            float4 sv = red4[tt];                                                \
            _Pragma("unroll")                                                    \
            for (int seg = 1; seg < 8; ++seg) {                                  \
                float4 v = red4[seg * 256 + tt];                                 \
                sv.x += v.x; sv.y += v.y; sv.z += v.z; sv.w += v.w;              \
            }                                                                    \
            int row_ = tt >> 3;                                                  \
            int col_ = (tt & 7) * 4;                                             \
            float* op = out + obase + (size_t)(O) * (C_CH * C_CH)                \
                      + (size_t)(c0 + row_) * C_CH + d0 + col_;                  \
            *(float4*)op = sv;                                                   \
            float ss = sv.x * sv.x + sv.y * sv.y + sv.z * sv.z + sv.w * sv.w;    \
            _Pragma("unroll")                                                    \
            for (int off = 32; off; off >>= 1) ss += __shfl_down(ss, off, 64);   \
            if (lane == 0) wsum[tt >> 6] = ss;                                   \
        }                                                                        \
        __syncthreads();                                                         \
        if (tt == 0) atomicAdd(&norms[b * NO + (O)],                             \
                               wsum[0] + wsum[1] + wsum[2] + wsum[3]);           \
    } while (0)

    short8 A[4];        // single-buffer A stream: overwrite-after-last-use
    short8 U[2][4];     // B rows: ping-pong (current / next)

    // ---------------- PASS A: offsets 3 (0,-1) and 4 (0,0) : A[g] x {Um,U}[g] ----------------
    {
        floatx16 acc3, acc4;
        #pragma unroll
        for (int e = 0; e < 16; ++e) { acc3[e] = 0.0f; acc4[e] = 0.0f; }

        #pragma unroll
        for (int s = 0; s < 4; ++s) {
            A[s]    = A8[(8 * h0 + 2 * s) * 32 + laneoff];
            U[0][s] = B8[(8 * h0 + 2 * s) * 32 + laneoff];
        }

        #pragma unroll
        for (int r = 0; r < 8; ++r) {
            int g = h0 + r;
            const int cu = r & 1, nx = (r + 1) & 1;
            int gn = (g + 1 < 64) ? g + 1 : 63;     // prefetch row (dummy at tail)
            #pragma unroll
            for (int s = 0; s < 4; ++s) {
                short8 Um;
                MAKE_SHIFT_M(U[cu], s, Um);
                acc4 = __builtin_amdgcn_mfma_f32_32x32x16_bf16(A[s], U[cu][s], acc4, 0, 0, 0);
                acc3 = __builtin_amdgcn_mfma_f32_32x32x16_bf16(A[s], Um,       acc3, 0, 0, 0);
                A[s]     = A8[(8 * gn + 2 * s) * 32 + laneoff];   // row g+1 (next r)
                U[nx][s] = B8[(8 * gn + 2 * s) * 32 + laneoff];
            }
        }

        REDUCE_STORE(acc3, 3);
        REDUCE_STORE(acc4, 4);
    }

    // ---------------- PASS B: offsets 0,1,2 (dy=-1) : A[g+1] x {Um,U,Up}[g], g<=62 ----------------
    {
        floatx16 acc0, acc1, acc2;
        #pragma unroll
        for (int e = 0; e < 16; ++e) { acc0[e] = 0.0f; acc1[e] = 0.0f; acc2[e] = 0.0f; }

        #pragma unroll
        for (int s = 0; s < 4; ++s) {
            A[s]    = A8[(8 * (h0 + 1) + 2 * s) * 32 + laneoff];  // A row g+1 for g=h0
            U[0][s] = B8[(8 * h0 + 2 * s) * 32 + laneoff];
        }

        // h = 0 boundary: dy=-1 offsets pair center row 0 with clamped side row 0
        if (h0 == 0) {
            #pragma unroll
            for (int s = 0; s < 4; ++s) {
                short8 A0 = A8[(2 * s) * 32 + laneoff];           // A row 0
                short8 Um, Up;
                MAKE_SHIFT(U[0], s, Um, Up);
                acc0 = __builtin_amdgcn_mfma_f32_32x32x16_bf16(A0, Um,      acc0, 0, 0, 0);
                acc1 = __builtin_amdgcn_mfma_f32_32x32x16_bf16(A0, U[0][s], acc1, 0, 0, 0);
                acc2 = __builtin_amdgcn_mfma_f32_32x32x16_bf16(A0, Up,      acc2, 0, 0, 0);
            }
        }

        #pragma unroll
        for (int r = 0; r < 8; ++r) {
            int g = h0 + r;
            const int cu = r & 1, nx = (r + 1) & 1;
            int gn  = (g + 1 < 64) ? g + 1 : 63;    // next U row
            int gnA = (g + 2 < 64) ? g + 2 : 63;    // next A row = (g+1)+1
            #pragma unroll
            for (int s = 0; s < 4; ++s) {
                if (r < 7 || g < 63) {              // dy=-1 sum runs g = 0..62
                    short8 Um, Up;
                    MAKE_SHIFT(U[cu], s, Um, Up);
                    acc1 = __builtin_amdgcn_mfma_f32_32x32x16_bf16(A[s], U[cu][s], acc1, 0, 0, 0);
                    acc0 = __builtin_amdgcn_mfma_f32_32x32x16_bf16(A[s], Um,       acc0, 0, 0, 0);
                    acc2 = __builtin_amdgcn_mfma_f32_32x32x16_bf16(A[s], Up,       acc2, 0, 0, 0);
                }
                A[s]     = A8[(8 * gnA + 2 * s) * 32 + laneoff];
                U[nx][s] = B8[(8 * gn  + 2 * s) * 32 + laneoff];
            }
        }

        REDUCE_STORE(acc0, 0);
        REDUCE_STORE(acc1, 1);
        REDUCE_STORE(acc2, 2);
    }
#undef REDUCE_STORE
}

// ---------------- Kernel 3: scale by 1/norm ----------------
__global__ __launch_bounds__(256) void scale_kernel(float* __restrict__ out,
                                                    const float* __restrict__ norms) {
    int g  = blockIdx.x * 256 + threadIdx.x;    // float4 index, 737,280 total
    int bo = blockIdx.x / 36;                   // 9216 float4 per (b,o)
    float s = norms[bo];
    float inv = 1.0f / fmaxf(sqrtf(s), 1e-12f);
    float4 v = ((const float4*)out)[g];
    v.x *= inv; v.y *= inv; v.z *= inv; v.w *= inv;
    ((float4*)out)[g] = v;
}

extern "C" void kernel_launch(void* const* d_in, const int* in_sizes, int n_in,
                              void* d_out, int out_size, void* d_ws, size_t ws_size,
                              hipStream_t stream) {
    const float* x = (const float*)d_in[0];
    float* out = (float*)d_out;
    float* norms = (float*)d_ws;                                   // 80 floats (+pad)
    unsigned short* xb = (unsigned short*)((char*)d_ws + 512);     // 25,165,824 B bf16 tiled

    convert_kernel<<<6144, 256, 0, stream>>>(x, xb, norms);
    cofe_gemm<<<576, 512, 0, stream>>>(xb, out, norms);
    scale_kernel<<<2880, 256, 0, stream>>>(out, norms);
}